// Round 2
// baseline (209.927 us; speedup 1.0000x reference)
//
#include <hip/hip_runtime.h>

// ---------------------------------------------------------------------------
// Gate_16501264351574: conv3x3(256ch -> 64 experts) + sigmoid + top8 + softmax
//   x:      [16, 256, 64, 64] f32
//   gate_w: [64, 256, 3, 3]   f32
//   bias:   [64]              f32
// out (flat f32): weights [16,8,64,64] | indices-as-float [16,8,64,64] | counts[64]
//
// R2: precision fixes for the counts check (R1: 192 vs thr 179.2):
//  - scores kept fp32 through the top-k transpose (two-phase LDS reuse)
//  - gate_w split into bf16 hi+lo, A*hi + A*lo accumulation (removes w-quant)
// ---------------------------------------------------------------------------

typedef __attribute__((ext_vector_type(8))) short short8;
typedef __attribute__((ext_vector_type(4))) float f32x4;

#define LOG2E 1.44269504f

__device__ __forceinline__ unsigned short f2bf(float f) {
    unsigned u = __float_as_uint(f);
    u += 0x7fffu + ((u >> 16) & 1u);          // round-to-nearest-even
    return (unsigned short)(u >> 16);
}
__device__ __forceinline__ float bf2f(unsigned short s) {
    return __uint_as_float(((unsigned)s) << 16);
}

constexpr int WB_FRAGS = 9 * 8 * 4 * 64;      // 18432 uint4 per array (hi, lo)

// ---------------------------------------------------------------------------
// Prep: repack gate_w into per-lane B-fragment layout, bf16 hi + residual lo.
//   wB[((t*8 + kst)*4 + nt)*64 + lane] = 8 bf16 (16B):
//     e = nt*16 + (lane&15); c = kst*32 + (lane>>4)*8 + j; tap t = kh*3+kw
//   wBlo at uint4 offset WB_FRAGS, same indexing, lo = bf16(w - hi)
// ---------------------------------------------------------------------------
__global__ __launch_bounds__(256) void gate_prep(const float* __restrict__ gw,
                                                 unsigned short* __restrict__ wB) {
    int g = blockIdx.x * 256 + threadIdx.x;   // 0..18431
    if (g >= WB_FRAGS) return;
    int lane = g & 63;
    int nt   = (g >> 6) & 3;
    int kst  = (g >> 8) & 7;
    int t    = g >> 11;                        // 0..8
    int e  = nt * 16 + (lane & 15);
    int c0 = kst * 32 + (lane >> 4) * 8;
    int kh = t / 3, kw = t % 3;
    unsigned short oh[8], ol[8];
#pragma unroll
    for (int j = 0; j < 8; ++j) {
        float f  = gw[(e * 256 + c0 + j) * 9 + kh * 3 + kw];
        unsigned short h = f2bf(f);
        oh[j] = h;
        ol[j] = f2bf(f - bf2f(h));
    }
    uint4 ph, pl;
    ph.x = (unsigned)oh[0] | ((unsigned)oh[1] << 16);
    ph.y = (unsigned)oh[2] | ((unsigned)oh[3] << 16);
    ph.z = (unsigned)oh[4] | ((unsigned)oh[5] << 16);
    ph.w = (unsigned)oh[6] | ((unsigned)oh[7] << 16);
    pl.x = (unsigned)ol[0] | ((unsigned)ol[1] << 16);
    pl.y = (unsigned)ol[2] | ((unsigned)ol[3] << 16);
    pl.z = (unsigned)ol[4] | ((unsigned)ol[5] << 16);
    pl.w = (unsigned)ol[6] | ((unsigned)ol[7] << 16);
    ((uint4*)wB)[g]            = ph;
    ((uint4*)wB)[g + WB_FRAGS] = pl;
}

// ---------------------------------------------------------------------------
// Main kernel. Grid 256 (b = blk&15 -> XCD swizzle, hb = blk>>4 -> 4 rows).
// 256 threads = 4 waves; wave rw computes output row h0+rw (64 pos x 64 exp).
// LDS: xs double buffer [2][6 rows][66 w'][40 c] bf16 (63360B); epilogue
//      reuses it as fp32 scores [128][68] (two phases); bias(256B) hist(256B).
// ---------------------------------------------------------------------------
constexpr int CSTR    = 40;                  // bf16 per (row, w') line (pad 32->40)
constexpr int XSLINE  = 66 * CSTR;           // 2640 el
constexpr int XSBUF   = 6 * XSLINE;          // 15840 el (31680 B)
constexpr int SSTR    = 68;                  // fp32 score row stride (272B, 16B-aligned)
constexpr int SMEM_XS = 2 * XSBUF * 2;       // 63360 B
constexpr int SMEM_TOT = SMEM_XS + 256 + 256;

__global__ __launch_bounds__(256, 1) void gate_main(
    const float* __restrict__ x, const float* __restrict__ bias,
    const unsigned short* __restrict__ wB, float* __restrict__ out) {
    extern __shared__ unsigned char smem[];
    unsigned short* xs0    = (unsigned short*)smem;            // [2][6][66][40]
    float*          scf    = (float*)smem;                     // alias: [128][68]
    float*          bias_s = (float*)(smem + SMEM_XS);
    int*            hist   = (int*)(smem + SMEM_XS + 256);

    const int tid  = threadIdx.x;
    const int lane = tid & 63;
    const int rw   = tid >> 6;                 // wave id = output row in block
    const int b    = blockIdx.x & 15;
    const int h0   = (blockIdx.x >> 4) * 4;

    if (tid < 64) { hist[tid] = 0; bias_s[tid] = bias[tid]; }

    // staging slot 0: rows 0..3 (all threads); slot 1: rows 4..5 (tid < 128)
    const int  r0   = tid >> 6;
    const int  ws_  = tid & 63;
    const bool two  = (tid < 128);
    const int  r1   = 4 + (tid >> 6);          // valid only when two

    float va[32], vb[32];

    auto stage_load = [&](int q) {
        const int cb  = q * 32;
        const int gr0 = h0 - 1 + r0;
        const float* p0 = x + (((b * 256 + cb) * 64 + gr0) * 64 + ws_);
        if (gr0 >= 0 && gr0 < 64) {
#pragma unroll
            for (int u = 0; u < 32; ++u) va[u] = p0[u * 4096];
        } else {
#pragma unroll
            for (int u = 0; u < 32; ++u) va[u] = 0.f;
        }
        if (two) {
            const int gr1 = h0 - 1 + r1;
            const float* p1 = x + (((b * 256 + cb) * 64 + gr1) * 64 + ws_);
            if (gr1 >= 0 && gr1 < 64) {
#pragma unroll
                for (int u = 0; u < 32; ++u) vb[u] = p1[u * 4096];
            } else {
#pragma unroll
                for (int u = 0; u < 32; ++u) vb[u] = 0.f;
            }
        }
    };

    auto stage_store = [&](unsigned short* dst) {
        unsigned short* d0 = dst + (r0 * 66 + (ws_ + 1)) * CSTR;
#pragma unroll
        for (int c8 = 0; c8 < 4; ++c8) {
            short8 pk;
#pragma unroll
            for (int j = 0; j < 8; ++j) pk[j] = (short)f2bf(va[c8 * 8 + j]);
            *(short8*)(d0 + c8 * 8) = pk;
        }
        if (two) {
            unsigned short* d1 = dst + (r1 * 66 + (ws_ + 1)) * CSTR;
#pragma unroll
            for (int c8 = 0; c8 < 4; ++c8) {
                short8 pk;
#pragma unroll
                for (int j = 0; j < 8; ++j) pk[j] = (short)f2bf(vb[c8 * 8 + j]);
                *(short8*)(d1 + c8 * 8) = pk;
            }
        }
        // halo columns w'=0 and w'=65 are always zero (image W edges)
        if (tid < 48) {
            int hr = tid >> 3, hc = (tid >> 2) & 1, hg = tid & 3;
            short8 z = {0, 0, 0, 0, 0, 0, 0, 0};
            *(short8*)(dst + (hr * 66 + hc * 65) * CSTR + hg * 8) = z;
        }
    };

    f32x4 acc[4][4];
#pragma unroll
    for (int mt = 0; mt < 4; ++mt)
#pragma unroll
        for (int nt = 0; nt < 4; ++nt) acc[mt][nt] = (f32x4){0.f, 0.f, 0.f, 0.f};

    auto compute = [&](int q, const unsigned short* buf) {
#pragma unroll
        for (int t = 0; t < 9; ++t) {
            const int kh = t / 3, kw = t % 3;
            // A[m=lane&15][k=(lane>>4)*8+j]; m -> position p = mt*16 + (lane&15)
            const unsigned short* abase =
                buf + ((rw + kh) * 66 + kw + (lane & 15)) * CSTR + (lane >> 4) * 8;
            short8 afr[4];
#pragma unroll
            for (int mt = 0; mt < 4; ++mt)
                afr[mt] = *(const short8*)(abase + mt * 16 * CSTR);
            const uint4* wbp = (const uint4*)wB + ((t * 8 + q) * 4) * 64 + lane;
#pragma unroll
            for (int nt = 0; nt < 4; ++nt) {
                short8 bhi = *(const short8*)(wbp + nt * 64);
                short8 blo = *(const short8*)(wbp + nt * 64 + WB_FRAGS);
#pragma unroll
                for (int mt = 0; mt < 4; ++mt)
                    acc[mt][nt] = __builtin_amdgcn_mfma_f32_16x16x32_bf16(
                        afr[mt], bhi, acc[mt][nt], 0, 0, 0);
#pragma unroll
                for (int mt = 0; mt < 4; ++mt)
                    acc[mt][nt] = __builtin_amdgcn_mfma_f32_16x16x32_bf16(
                        afr[mt], blo, acc[mt][nt], 0, 0, 0);
            }
        }
    };

    // software pipeline: loads for chunk q+1 in flight across chunk q's MFMAs
    stage_load(0);
    stage_store(xs0);
    __syncthreads();
#pragma unroll 1
    for (int q = 0; q < 8; ++q) {
        const unsigned short* cur = xs0 + (q & 1) * XSBUF;
        if (q < 7) {
            stage_load(q + 1);
            compute(q, cur);
            stage_store(xs0 + ((q + 1) & 1) * XSBUF);
        } else {
            compute(q, cur);
        }
        __syncthreads();
    }

    // ------------------------------------------------------------------
    // Epilogue, two phases of 128 positions (fp32 scores through LDS).
    // C/D layout: col=lane&15 (expert), row=(lane>>4)*4+reg (position).
    // ------------------------------------------------------------------
#pragma unroll 1
    for (int ph = 0; ph < 2; ++ph) {
        if ((rw >> 1) == ph) {
            const int prow = (rw & 1) * 64;
#pragma unroll
            for (int mt = 0; mt < 4; ++mt)
#pragma unroll
                for (int nt = 0; nt < 4; ++nt)
#pragma unroll
                    for (int rr = 0; rr < 4; ++rr) {
                        float v = acc[mt][nt][rr];
                        float s = 1.f / (1.f + __builtin_amdgcn_exp2f(-v * LOG2E));
                        int p = prow + mt * 16 + ((lane >> 4) << 2) + rr;
                        int e = nt * 16 + (lane & 15);
                        scf[p * SSTR + e] = s;
                    }
        }
        __syncthreads();
        if (tid < 128) {
            const float* row = scf + tid * SSTR;
            float tv[8];
            int   ti[8];
#pragma unroll
            for (int k = 0; k < 8; ++k) { tv[k] = -3.0e38f; ti[k] = 0; }
#pragma unroll
            for (int j4 = 0; j4 < 16; ++j4) {
                f32x4 blk = *(const f32x4*)(row + j4 * 4);
#pragma unroll
                for (int j = 0; j < 4; ++j) {
                    int   e  = j4 * 4 + j;
                    float s  = blk[j];
                    float bs = s + bias_s[e];
                    if (bs > tv[7]) {
                        tv[7] = bs; ti[7] = e;
#pragma unroll
                        for (int k = 7; k > 0; --k) {
                            float fa = tv[k - 1], fb = tv[k];
                            int   ia = ti[k - 1], ib = ti[k];
                            bool  sw = fb > fa;
                            tv[k - 1] = sw ? fb : fa; tv[k] = sw ? fa : fb;
                            ti[k - 1] = sw ? ib : ia; ti[k] = sw ? ia : ib;
                        }
                    }
                }
            }
            // softmax over UNbiased scores of the selected 8
            float u[8], mx = -3.0e38f;
#pragma unroll
            for (int k = 0; k < 8; ++k) { u[k] = tv[k] - bias_s[ti[k]]; mx = fmaxf(mx, u[k]); }
            float ex[8], sum = 0.f;
#pragma unroll
            for (int k = 0; k < 8; ++k) { ex[k] = __builtin_amdgcn_exp2f((u[k] - mx) * LOG2E); sum += ex[k]; }
            float inv = 1.f / sum;

            int pos = ph * 128 + tid;
            int hh = h0 + (pos >> 6), ww = pos & 63;
            int obase = (b * 8) * 4096 + hh * 64 + ww;
#pragma unroll
            for (int k = 0; k < 8; ++k) {
                out[obase + k * 4096]          = ex[k] * inv;       // weights
                out[524288 + obase + k * 4096] = (float)ti[k];      // indices (as f32)
                atomicAdd(&hist[ti[k]], 1);
            }
        }
        __syncthreads();
    }
    if (tid < 64) atomicAdd(out + 1048576 + tid, (float)hist[tid]);  // counts (as f32)
}

// ---------------------------------------------------------------------------
extern "C" void kernel_launch(void* const* d_in, const int* in_sizes, int n_in,
                              void* d_out, int out_size, void* d_ws, size_t ws_size,
                              hipStream_t stream) {
    const float* x    = (const float*)d_in[0];
    const float* gw   = (const float*)d_in[1];
    const float* bias = (const float*)d_in[2];
    float* out = (float*)d_out;
    unsigned short* wB = (unsigned short*)d_ws;   // 2 * 294912 B needed

    // counts region is accumulated with atomics -> zero it (d_out is poisoned
    // before every timed launch)
    hipMemsetAsync((char*)d_out + (size_t)1048576 * sizeof(float), 0,
                   64 * sizeof(float), stream);
    gate_prep<<<72, 256, 0, stream>>>(gw, wB);
    gate_main<<<256, 256, SMEM_TOT, stream>>>(x, bias, wB, out);
}

// Round 3
// 208.946 us; speedup vs baseline: 1.0047x; 1.0047x over previous
//
#include <hip/hip_runtime.h>

// ---------------------------------------------------------------------------
// Gate_16501264351574: conv3x3(256ch -> 64 experts) + sigmoid + top8 + softmax
//   x: [16,256,64,64] f32, gate_w: [64,256,3,3] f32, bias: [64] f32
// out (flat f32): weights [16,8,64,64] | indices-as-f32 [16,8,64,64] | counts[64]
//
// R3: split-K for occupancy. R2 was 1 block/CU = 1 wave/SIMD = 95% stall.
//  - gate_partial: grid 1024 = 16 img x 16 rowblk x 4 ksplit, single-buffer
//    LDS (31.7KB), launch_bounds(256,3) -> 3 blocks/CU = 3 waves/SIMD.
//    Partial logits accumulated with fp32 atomicAdd into d_ws scratch.
//  - gate_final: grid 256, coalesced logit read -> sigmoid -> top8 epilogue.
// ---------------------------------------------------------------------------

typedef __attribute__((ext_vector_type(8))) short short8;
typedef __attribute__((ext_vector_type(4))) float f32x4;

#define LOG2E 1.44269504f

__device__ __forceinline__ unsigned short f2bf(float f) {
    unsigned u = __float_as_uint(f);
    u += 0x7fffu + ((u >> 16) & 1u);          // round-to-nearest-even
    return (unsigned short)(u >> 16);
}
__device__ __forceinline__ float bf2f(unsigned short s) {
    return __uint_as_float(((unsigned)s) << 16);
}

constexpr int WB_FRAGS = 9 * 8 * 4 * 64;      // 18432 uint4 per array (hi, lo)

// ---------------------------------------------------------------------------
// Prep: repack gate_w into per-lane B-fragment layout, bf16 hi + residual lo.
//   wB[((t*8 + q)*4 + nt)*64 + lane]: e = nt*16+(lane&15), c = q*32+(lane>>4)*8+j
// ---------------------------------------------------------------------------
__global__ __launch_bounds__(256) void gate_prep(const float* __restrict__ gw,
                                                 unsigned short* __restrict__ wB) {
    int g = blockIdx.x * 256 + threadIdx.x;
    if (g >= WB_FRAGS) return;
    int lane = g & 63;
    int nt   = (g >> 6) & 3;
    int kst  = (g >> 8) & 7;
    int t    = g >> 11;
    int e  = nt * 16 + (lane & 15);
    int c0 = kst * 32 + (lane >> 4) * 8;
    int kh = t / 3, kw = t % 3;
    unsigned short oh[8], ol[8];
#pragma unroll
    for (int j = 0; j < 8; ++j) {
        float f  = gw[(e * 256 + c0 + j) * 9 + kh * 3 + kw];
        unsigned short h = f2bf(f);
        oh[j] = h;
        ol[j] = f2bf(f - bf2f(h));
    }
    uint4 ph, pl;
    ph.x = (unsigned)oh[0] | ((unsigned)oh[1] << 16);
    ph.y = (unsigned)oh[2] | ((unsigned)oh[3] << 16);
    ph.z = (unsigned)oh[4] | ((unsigned)oh[5] << 16);
    ph.w = (unsigned)oh[6] | ((unsigned)oh[7] << 16);
    pl.x = (unsigned)ol[0] | ((unsigned)ol[1] << 16);
    pl.y = (unsigned)ol[2] | ((unsigned)ol[3] << 16);
    pl.z = (unsigned)ol[4] | ((unsigned)ol[5] << 16);
    pl.w = (unsigned)ol[6] | ((unsigned)ol[7] << 16);
    ((uint4*)wB)[g]            = ph;
    ((uint4*)wB)[g + WB_FRAGS] = pl;
}

// ---------------------------------------------------------------------------
// Partial-K conv kernel. blk = (b*16 + rb)*4 + ks. Block: 4 output rows,
// channels [ks*64, ks*64+64) as 2 chunks of 32. 4 waves, wave rw = 1 row.
// ---------------------------------------------------------------------------
constexpr int CSTR   = 40;                   // bf16 per (row,w') line (pad 32->40)
constexpr int XSLINE = 66 * CSTR;            // 2640
constexpr int XSBUF  = 6 * XSLINE;           // 15840 shorts = 31680 B

__global__ __launch_bounds__(256, 3) void gate_partial(
    const float* __restrict__ x, const unsigned short* __restrict__ wB,
    float* __restrict__ logits) {
    __shared__ unsigned short xs[XSBUF];

    const int tid  = threadIdx.x;
    const int lane = tid & 63;
    const int rw   = tid >> 6;
    const int blk  = blockIdx.x;
    const int ks   = blk & 3;
    const int rb   = (blk >> 2) & 15;
    const int b    = blk >> 6;
    const int h0   = rb * 4;

    // staging: slot 0 rows 0..3 (all threads); slot 1 rows 4..5 (tid<128)
    const int  r0  = tid >> 6;
    const int  ws_ = tid & 63;
    const bool two = (tid < 128);
    const int  r1  = 4 + (tid >> 6);

    float va[32], vb[32];

    auto stage_load = [&](int q) {
        const int cb  = q * 32;
        const int gr0 = h0 - 1 + r0;
        const float* p0 = x + (((b * 256 + cb) * 64 + gr0) * 64 + ws_);
        if (gr0 >= 0 && gr0 < 64) {
#pragma unroll
            for (int u = 0; u < 32; ++u) va[u] = p0[u * 4096];
        } else {
#pragma unroll
            for (int u = 0; u < 32; ++u) va[u] = 0.f;
        }
        if (two) {
            const int gr1 = h0 - 1 + r1;
            const float* p1 = x + (((b * 256 + cb) * 64 + gr1) * 64 + ws_);
            if (gr1 >= 0 && gr1 < 64) {
#pragma unroll
                for (int u = 0; u < 32; ++u) vb[u] = p1[u * 4096];
            } else {
#pragma unroll
                for (int u = 0; u < 32; ++u) vb[u] = 0.f;
            }
        }
    };

    auto stage_store = [&]() {
        unsigned short* d0 = xs + (r0 * 66 + (ws_ + 1)) * CSTR;
#pragma unroll
        for (int c8 = 0; c8 < 4; ++c8) {
            short8 pk;
#pragma unroll
            for (int j = 0; j < 8; ++j) pk[j] = (short)f2bf(va[c8 * 8 + j]);
            *(short8*)(d0 + c8 * 8) = pk;
        }
        if (two) {
            unsigned short* d1 = xs + (r1 * 66 + (ws_ + 1)) * CSTR;
#pragma unroll
            for (int c8 = 0; c8 < 4; ++c8) {
                short8 pk;
#pragma unroll
                for (int j = 0; j < 8; ++j) pk[j] = (short)f2bf(vb[c8 * 8 + j]);
                *(short8*)(d1 + c8 * 8) = pk;
            }
        }
        if (tid < 48) {  // halo columns w'=0 and w'=65 are zero (W edges)
            int hr = tid >> 3, hc = (tid >> 2) & 1, hg = tid & 3;
            short8 z = {0, 0, 0, 0, 0, 0, 0, 0};
            *(short8*)(xs + (hr * 66 + hc * 65) * CSTR + hg * 8) = z;
        }
    };

    f32x4 acc[4][4];
#pragma unroll
    for (int mt = 0; mt < 4; ++mt)
#pragma unroll
        for (int nt = 0; nt < 4; ++nt) acc[mt][nt] = (f32x4){0.f, 0.f, 0.f, 0.f};

    auto compute = [&](int q) {
#pragma unroll
        for (int t = 0; t < 9; ++t) {
            const int kh = t / 3, kw = t % 3;
            const unsigned short* abase =
                xs + ((rw + kh) * 66 + kw + (lane & 15)) * CSTR + (lane >> 4) * 8;
            short8 afr[4];
#pragma unroll
            for (int mt = 0; mt < 4; ++mt)
                afr[mt] = *(const short8*)(abase + mt * 16 * CSTR);
            const uint4* wbp = (const uint4*)wB + ((t * 8 + q) * 4) * 64 + lane;
#pragma unroll
            for (int nt = 0; nt < 4; ++nt) {
                short8 bhi = *(const short8*)(wbp + nt * 64);
                short8 blo = *(const short8*)(wbp + nt * 64 + WB_FRAGS);
#pragma unroll
                for (int mt = 0; mt < 4; ++mt)
                    acc[mt][nt] = __builtin_amdgcn_mfma_f32_16x16x32_bf16(
                        afr[mt], bhi, acc[mt][nt], 0, 0, 0);
#pragma unroll
                for (int mt = 0; mt < 4; ++mt)
                    acc[mt][nt] = __builtin_amdgcn_mfma_f32_16x16x32_bf16(
                        afr[mt], blo, acc[mt][nt], 0, 0, 0);
            }
        }
    };

    const int q0 = ks * 2, q1 = q0 + 1;
    stage_load(q0);
    stage_store();
    __syncthreads();
    compute(q0);
    __syncthreads();
    stage_load(q1);
    stage_store();
    __syncthreads();
    compute(q1);

    // accumulate partial logits. C/D: col=lane&15 (expert), row=(lane>>4)*4+reg
    const int prow = (lane >> 4) << 2;
    const int gr   = (b * 64 + h0 + rw) * 64;   // row base in flat pos space
#pragma unroll
    for (int mt = 0; mt < 4; ++mt)
#pragma unroll
        for (int nt = 0; nt < 4; ++nt)
#pragma unroll
            for (int rr = 0; rr < 4; ++rr) {
                int p = mt * 16 + prow + rr;
                int e = nt * 16 + (lane & 15);
                atomicAdd(&logits[(size_t)(gr + p) * 64 + e], acc[mt][nt][rr]);
            }
}

// ---------------------------------------------------------------------------
// Final: grid 256 x 256 thr; block g handles positions [g*256, g*256+256).
// Coalesced logit load -> sigmoid -> LDS [256][68] -> per-thread top8.
// ---------------------------------------------------------------------------
constexpr int FSTR = 68;
constexpr int FIN_SMEM = 256 * FSTR * 4 + 256 + 256;

__global__ __launch_bounds__(256) void gate_final(
    const float* __restrict__ logits, const float* __restrict__ bias,
    float* __restrict__ out) {
    extern __shared__ unsigned char smem[];
    float* scf    = (float*)smem;                            // [256][68]
    float* bias_s = (float*)(smem + 256 * FSTR * 4);
    int*   hist   = (int*)(smem + 256 * FSTR * 4 + 256);

    const int tid = threadIdx.x;
    const int g   = blockIdx.x;
    if (tid < 64) { bias_s[tid] = bias[tid]; hist[tid] = 0; }

    const float* src = logits + (size_t)g * 16384;
#pragma unroll
    for (int i = 0; i < 16; ++i) {
        int s = i * 256 + tid;
        f32x4 v = *(const f32x4*)(src + 4 * s);
        f32x4 sg;
#pragma unroll
        for (int j = 0; j < 4; ++j)
            sg[j] = 1.f / (1.f + __builtin_amdgcn_exp2f(-v[j] * LOG2E));
        int pr = s >> 4, col = (s & 15) * 4;
        *(f32x4*)(scf + pr * FSTR + col) = sg;
    }
    __syncthreads();

    // top-8 of 64, jax tie-break (lower index first): ascending scan, strict '>'
    const float* row = scf + tid * FSTR;
    float tv[8];
    int   ti[8];
#pragma unroll
    for (int k = 0; k < 8; ++k) { tv[k] = -3.0e38f; ti[k] = 0; }
#pragma unroll
    for (int j4 = 0; j4 < 16; ++j4) {
        f32x4 blk = *(const f32x4*)(row + j4 * 4);
#pragma unroll
        for (int j = 0; j < 4; ++j) {
            int   e  = j4 * 4 + j;
            float bs = blk[j] + bias_s[e];
            if (bs > tv[7]) {
                tv[7] = bs; ti[7] = e;
#pragma unroll
                for (int k = 7; k > 0; --k) {
                    float fa = tv[k - 1], fb = tv[k];
                    int   ia = ti[k - 1], ib = ti[k];
                    bool  sw = fb > fa;
                    tv[k - 1] = sw ? fb : fa; tv[k] = sw ? fa : fb;
                    ti[k - 1] = sw ? ib : ia; ti[k] = sw ? ia : ib;
                }
            }
        }
    }
    // softmax over UNbiased scores of the selected 8
    float u[8], mx = -3.0e38f;
#pragma unroll
    for (int k = 0; k < 8; ++k) { u[k] = tv[k] - bias_s[ti[k]]; mx = fmaxf(mx, u[k]); }
    float ex[8], sum = 0.f;
#pragma unroll
    for (int k = 0; k < 8; ++k) { ex[k] = __builtin_amdgcn_exp2f((u[k] - mx) * LOG2E); sum += ex[k]; }
    float inv = 1.f / sum;

    int gpos = g * 256 + tid;
    int bb   = gpos >> 12, rem = gpos & 4095;
    int obase = bb * 32768 + rem;
#pragma unroll
    for (int k = 0; k < 8; ++k) {
        out[obase + k * 4096]          = ex[k] * inv;       // weights
        out[524288 + obase + k * 4096] = (float)ti[k];      // indices (as f32)
        atomicAdd(&hist[ti[k]], 1);
    }
    __syncthreads();
    if (tid < 64) atomicAdd(out + 1048576 + tid, (float)hist[tid]);  // counts
}

// ---------------------------------------------------------------------------
extern "C" void kernel_launch(void* const* d_in, const int* in_sizes, int n_in,
                              void* d_out, int out_size, void* d_ws, size_t ws_size,
                              hipStream_t stream) {
    const float* x    = (const float*)d_in[0];
    const float* gw   = (const float*)d_in[1];
    const float* bias = (const float*)d_in[2];
    float* out = (float*)d_out;

    unsigned short* wB = (unsigned short*)d_ws;                 // 589824 B (hi+lo)
    float* logits = (float*)((char*)d_ws + 589824);             // 16777216 B

    hipMemsetAsync(logits, 0, (size_t)16777216, stream);
    hipMemsetAsync((char*)d_out + (size_t)1048576 * sizeof(float), 0,
                   64 * sizeof(float), stream);
    gate_prep<<<72, 256, 0, stream>>>(gw, wB);
    gate_partial<<<1024, 256, 0, stream>>>(x, wB, logits);
    gate_final<<<256, 256, FIN_SMEM, stream>>>(logits, bias, out);
}

// Round 4
// 172.974 us; speedup vs baseline: 1.2136x; 1.2080x over previous
//
#include <hip/hip_runtime.h>

// ---------------------------------------------------------------------------
// Gate_16501264351574: conv3x3(256ch -> 64 experts) + sigmoid + top8 + softmax
//   x: [16,256,64,64] f32, gate_w: [64,256,3,3] f32, bias: [64] f32
// out (flat f32): weights [16,8,64,64] | indices-as-f32 [16,8,64,64] | counts[64]
//
// R4: single fused main kernel, long K-loop (8 chunks x 9 taps), f16 MFMA
// (f16 quant noise 8x below bf16 -> no hi/lo needed), x reg->LDS dbuf,
// B staged per-chunk into LDS (dedupes L2 traffic 4x), grid 512 = 2 blk/CU.
// ---------------------------------------------------------------------------

typedef _Float16 half8 __attribute__((ext_vector_type(8)));
typedef __attribute__((ext_vector_type(4))) float f32x4;

#define LOG2E 1.44269504f

__device__ __forceinline__ unsigned short f2h_bits(float f) {
    _Float16 h = (_Float16)f;                  // v_cvt_f16_f32, RNE
    unsigned short b;
    __builtin_memcpy(&b, &h, 2);
    return b;
}

constexpr int WB_U4 = 8 * 9 * 4 * 64;          // 18432 uint4 = 294912 B

// ---------------------------------------------------------------------------
// Prep: repack gate_w -> f16 B-fragments, CHUNK-CONTIGUOUS layout:
//   wB_u4[((q*9 + t)*4 + nt)*64 + lane] : e = nt*16+(lane&15),
//   c = q*32+(lane>>4)*8+j, tap t = kh*3+kw
// ---------------------------------------------------------------------------
__global__ __launch_bounds__(256) void gate_prep(const float* __restrict__ gw,
                                                 unsigned short* __restrict__ wB) {
    int g = blockIdx.x * 256 + threadIdx.x;
    if (g >= WB_U4) return;
    int lane = g & 63;
    int nt   = (g >> 6) & 3;
    int rest = g >> 8;                          // q*9 + t
    int t = rest % 9, q = rest / 9;
    int e  = nt * 16 + (lane & 15);
    int c0 = q * 32 + (lane >> 4) * 8;
    unsigned short o[8];
#pragma unroll
    for (int j = 0; j < 8; ++j)
        o[j] = f2h_bits(gw[(e * 256 + c0 + j) * 9 + t]);
    uint4 pk;
    pk.x = (unsigned)o[0] | ((unsigned)o[1] << 16);
    pk.y = (unsigned)o[2] | ((unsigned)o[3] << 16);
    pk.z = (unsigned)o[4] | ((unsigned)o[5] << 16);
    pk.w = (unsigned)o[6] | ((unsigned)o[7] << 16);
    ((uint4*)wB)[g] = pk;
}

// ---------------------------------------------------------------------------
// Main. Grid 512: b = blk&15 (XCD swizzle: image -> one XCD), rp = blk>>4
// (row-pair, output rows 2rp..2rp+1). 256 thr = 4 waves; wave rw covers
// row 2rp+(rw>>1), w-half (rw&1)*32: 32 pos x 64 experts (mt=2, nt=4).
// LDS: xs dbuf [2][4 rows][66 w'][40c] f16 (42240B) + bbuf 2304 uint4
// (36864B) + bias(256) + hist(256) = 79616B -> 2 blocks/CU.
// ---------------------------------------------------------------------------
constexpr int CSTR  = 40;                      // shorts per (row,w') line
constexpr int XROW  = 66 * CSTR;               // 2640
constexpr int XSBUF = 4 * XROW;                // 10560 shorts = 21120 B
constexpr int SSTR  = 68;                      // fp32 score row stride

__global__ __launch_bounds__(256, 2) void gate_main(
    const float* __restrict__ x, const float* __restrict__ bias,
    const unsigned short* __restrict__ wB, float* __restrict__ out) {
    __shared__ unsigned short xs[2 * XSBUF];   // 42240 B (aliased by scf later)
    __shared__ uint4 bbuf[2304];               // 36864 B
    __shared__ float bias_s[64];
    __shared__ int   hist[64];

    const int tid  = threadIdx.x;
    const int lane = tid & 63;
    const int rw   = tid >> 6;
    const int blk  = blockIdx.x;
    const int b    = blk & 15;
    const int rp   = blk >> 4;                 // 0..31

    if (tid < 64) { bias_s[tid] = bias[tid]; hist[tid] = 0; }

    // ---- staging state ----
    const int r0  = tid >> 6;                  // slab row 0..3 this thread fills
    const int ws_ = tid & 63;                  // w coordinate
    const int gr  = rp * 2 - 1 + r0;           // global input row (-1..64)
    const bool rok = (gr >= 0 && gr < 64);

    float va[32];                              // x column (32 channels)
    uint4 vB[9];                               // B chunk slice (9 uint4/thread)

    auto load_x = [&](int q) {
        const float* p0 = x + (((b * 256 + q * 32) * 64 + gr) * 64 + ws_);
        if (rok) {
#pragma unroll
            for (int u = 0; u < 32; ++u) va[u] = p0[u * 4096];
        } else {
#pragma unroll
            for (int u = 0; u < 32; ++u) va[u] = 0.f;
        }
    };
    auto store_x = [&](unsigned short* dst) {
        unsigned short* d0 = dst + (r0 * 66 + (ws_ + 1)) * CSTR;
#pragma unroll
        for (int c8 = 0; c8 < 4; ++c8) {
            uint4 pk;
            pk.x = (unsigned)f2h_bits(va[c8*8+0]) | ((unsigned)f2h_bits(va[c8*8+1]) << 16);
            pk.y = (unsigned)f2h_bits(va[c8*8+2]) | ((unsigned)f2h_bits(va[c8*8+3]) << 16);
            pk.z = (unsigned)f2h_bits(va[c8*8+4]) | ((unsigned)f2h_bits(va[c8*8+5]) << 16);
            pk.w = (unsigned)f2h_bits(va[c8*8+6]) | ((unsigned)f2h_bits(va[c8*8+7]) << 16);
            *(uint4*)(d0 + c8 * 8) = pk;
        }
        if (tid < 32) {                        // halo cols w'=0,65 are zero
            int hr = tid >> 3, hc = (tid >> 2) & 1, hg = tid & 3;
            uint4 z = {0, 0, 0, 0};
            *(uint4*)(dst + (hr * 66 + hc * 65) * CSTR + hg * 8) = z;
        }
    };
    auto load_B = [&](int q) {
        const uint4* src = (const uint4*)wB + q * 2304 + tid;
#pragma unroll
        for (int k = 0; k < 9; ++k) vB[k] = src[k * 256];
    };
    auto store_B = [&]() {
#pragma unroll
        for (int k = 0; k < 9; ++k) bbuf[tid + k * 256] = vB[k];
    };

    f32x4 acc[2][4];
#pragma unroll
    for (int mt = 0; mt < 2; ++mt)
#pragma unroll
        for (int nt = 0; nt < 4; ++nt) acc[mt][nt] = (f32x4){0.f, 0.f, 0.f, 0.f};

    const int half_ = rw & 1, rloc = rw >> 1;

    auto compute = [&](const unsigned short* buf) {
#pragma unroll
        for (int t = 0; t < 9; ++t) {
            const int kh = t / 3, kw = t % 3;
            const unsigned short* abase =
                buf + ((rloc + kh) * 66 + half_ * 32 + kw + (lane & 15)) * CSTR +
                (lane >> 4) * 8;
            half8 afr[2];
#pragma unroll
            for (int mt = 0; mt < 2; ++mt)
                afr[mt] = *(const half8*)(abase + mt * 16 * CSTR);
            const uint4* bp = bbuf + t * 4 * 64 + lane;
#pragma unroll
            for (int nt = 0; nt < 4; ++nt) {
                half8 bfr = *(const half8*)(bp + nt * 64);
#pragma unroll
                for (int mt = 0; mt < 2; ++mt)
                    acc[mt][nt] = __builtin_amdgcn_mfma_f32_16x16x32_f16(
                        afr[mt], bfr, acc[mt][nt], 0, 0, 0);
            }
        }
    };

    // ---- pipelined K loop: 8 chunks of 32 channels ----
    load_x(0);
    load_B(0);
    store_x(xs);
    store_B();
    __syncthreads();
#pragma unroll 1
    for (int q = 0; q < 8; ++q) {
        const unsigned short* cur = xs + (q & 1) * XSBUF;
        if (q < 7) {
            load_x(q + 1);                     // in flight across compute
            load_B(q + 1);
            compute(cur);
            store_x(xs + ((q + 1) & 1) * XSBUF);  // other buffer: no readers
            __syncthreads();                   // all done reading bbuf(q)
            store_B();
            __syncthreads();                   // staging visible
        } else {
            compute(cur);
            __syncthreads();
        }
    }

    // ---- epilogue: sigmoid -> fp32 scores in LDS (alias xs) ----
    float* scf = (float*)xs;                   // [128][68] = 34816 B < 42240
#pragma unroll
    for (int mt = 0; mt < 2; ++mt)
#pragma unroll
        for (int nt = 0; nt < 4; ++nt)
#pragma unroll
            for (int rr = 0; rr < 4; ++rr) {
                float v = acc[mt][nt][rr];
                float s = 1.f / (1.f + __builtin_amdgcn_exp2f(-v * LOG2E));
                int m16 = ((lane >> 4) << 2) + rr;
                int p   = rloc * 64 + half_ * 32 + mt * 16 + m16;
                int e   = nt * 16 + (lane & 15);
                scf[p * SSTR + e] = s;
            }
    __syncthreads();

    if (tid < 128) {
        // top-8 of 64; jax tie-break (lower idx first): ascending scan + strict >
        const float* row = scf + tid * SSTR;
        float tv[8];
        int   ti[8];
#pragma unroll
        for (int k = 0; k < 8; ++k) { tv[k] = -3.0e38f; ti[k] = 0; }
#pragma unroll
        for (int j4 = 0; j4 < 16; ++j4) {
            f32x4 blkv = *(const f32x4*)(row + j4 * 4);
#pragma unroll
            for (int j = 0; j < 4; ++j) {
                int   e  = j4 * 4 + j;
                float bs = blkv[j] + bias_s[e];
                if (bs > tv[7]) {
                    tv[7] = bs; ti[7] = e;
#pragma unroll
                    for (int k = 7; k > 0; --k) {
                        float fa = tv[k - 1], fb = tv[k];
                        int   ia = ti[k - 1], ib = ti[k];
                        bool  sw = fb > fa;
                        tv[k - 1] = sw ? fb : fa; tv[k] = sw ? fa : fb;
                        ti[k - 1] = sw ? ib : ia; ti[k] = sw ? ia : ib;
                    }
                }
            }
        }
        // softmax over UNbiased scores of the selected 8
        float u[8], mx = -3.0e38f;
#pragma unroll
        for (int k = 0; k < 8; ++k) { u[k] = tv[k] - bias_s[ti[k]]; mx = fmaxf(mx, u[k]); }
        float ex[8], sum = 0.f;
#pragma unroll
        for (int k = 0; k < 8; ++k) { ex[k] = __builtin_amdgcn_exp2f((u[k] - mx) * LOG2E); sum += ex[k]; }
        float inv = 1.f / sum;

        int h = rp * 2 + (tid >> 6), w = tid & 63;
        int obase = b * 32768 + h * 64 + w;
#pragma unroll
        for (int k = 0; k < 8; ++k) {
            out[obase + k * 4096]          = ex[k] * inv;     // weights
            out[524288 + obase + k * 4096] = (float)ti[k];    // indices (as f32)
            atomicAdd(&hist[ti[k]], 1);
        }
    }
    __syncthreads();
    if (tid < 64) atomicAdd(out + 1048576 + tid, (float)hist[tid]);  // counts
}

// ---------------------------------------------------------------------------
extern "C" void kernel_launch(void* const* d_in, const int* in_sizes, int n_in,
                              void* d_out, int out_size, void* d_ws, size_t ws_size,
                              hipStream_t stream) {
    const float* x    = (const float*)d_in[0];
    const float* gw   = (const float*)d_in[1];
    const float* bias = (const float*)d_in[2];
    float* out = (float*)d_out;
    unsigned short* wB = (unsigned short*)d_ws;   // 294912 B

    hipMemsetAsync((char*)d_out + (size_t)1048576 * sizeof(float), 0,
                   64 * sizeof(float), stream);   // counts accumulate from 0
    gate_prep<<<72, 256, 0, stream>>>(gw, wB);
    gate_main<<<512, 256, 0, stream>>>(x, bias, wB, out);
}

// Round 5
// 167.320 us; speedup vs baseline: 1.2546x; 1.0338x over previous
//
#include <hip/hip_runtime.h>

// ---------------------------------------------------------------------------
// Gate_16501264351574: conv3x3(256ch -> 64 experts) + sigmoid + top8 + softmax
//   x: [16,256,64,64] f32, gate_w: [64,256,3,3] f32, bias: [64] f32
// out (flat f32): weights [16,8,64,64] | indices-as-f32 [16,8,64,64] | counts[64]
//
// R5: kill spills (R4: 126MB scratch writeback), raise occupancy.
//  - 1-row blocks, grid 1024; LDS 18KB; wave = 32pos x 32exp (mt=2,nt=2)
//  - B-fragments in registers per chunk (18 uint4), x staged batch-of-8
//  - launch_bounds(256,4): 128 VGPR cap, 4 blocks/CU = 16 waves/CU
// ---------------------------------------------------------------------------

typedef _Float16 half8 __attribute__((ext_vector_type(8)));
typedef __attribute__((ext_vector_type(4))) float f32x4;

#define LOG2E 1.44269504f

__device__ __forceinline__ unsigned short f2h_bits(float f) {
    _Float16 h = (_Float16)f;                  // v_cvt_f16_f32, RNE
    unsigned short b;
    __builtin_memcpy(&b, &h, 2);
    return b;
}

constexpr int WB_U4 = 8 * 9 * 4 * 64;          // 18432 uint4 = 294912 B

// ---------------------------------------------------------------------------
// Prep: gate_w -> f16 B-fragments, chunk-major:
//   wB_u4[((q*9 + t)*4 + nt)*64 + lane]: e = nt*16+(lane&15), c = q*32+(lane>>4)*8+j
// ---------------------------------------------------------------------------
__global__ __launch_bounds__(256) void gate_prep(const float* __restrict__ gw,
                                                 unsigned short* __restrict__ wB) {
    int g = blockIdx.x * 256 + threadIdx.x;
    if (g >= WB_U4) return;
    int lane = g & 63;
    int nt   = (g >> 6) & 3;
    int rest = g >> 8;                          // q*9 + t
    int t = rest % 9, q = rest / 9;
    int e  = nt * 16 + (lane & 15);
    int c0 = q * 32 + (lane >> 4) * 8;
    unsigned short o[8];
#pragma unroll
    for (int j = 0; j < 8; ++j)
        o[j] = f2h_bits(gw[(e * 256 + c0 + j) * 9 + t]);
    uint4 pk;
    pk.x = (unsigned)o[0] | ((unsigned)o[1] << 16);
    pk.y = (unsigned)o[2] | ((unsigned)o[3] << 16);
    pk.z = (unsigned)o[4] | ((unsigned)o[5] << 16);
    pk.w = (unsigned)o[6] | ((unsigned)o[7] << 16);
    ((uint4*)wB)[g] = pk;
}

// ---------------------------------------------------------------------------
// Main. Grid 1024: b = blk&15 (image -> XCD locality), r = blk>>4 (output row).
// 256 thr = 4 waves; wave rw: pos-half ph=rw>>1 (32 pos), expert-half eh=rw&1.
// LDS: xs [3 rows][66 w'][40 c] f16 (15.8KB) aliased by scf [64][68] f32
// (17.4KB) in epilogue; + bias(256) + hist(256) ~= 18KB -> LDS allows many
// blocks; VGPR cap 128 (launch_bounds 256,4) -> 4 blocks/CU = 16 waves/CU.
// ---------------------------------------------------------------------------
constexpr int CSTR  = 40;                      // shorts per (row,w') line
constexpr int SSTR  = 68;                      // fp32 score row stride
constexpr int SCF_B = 64 * SSTR * 4;           // 17408 B (> xs 15840 B)

__global__ __launch_bounds__(256, 4) void gate_main(
    const float* __restrict__ x, const float* __restrict__ bias,
    const unsigned short* __restrict__ wB, float* __restrict__ out) {
    __shared__ unsigned char smem[SCF_B + 512];
    unsigned short* xs     = (unsigned short*)smem;   // [3][66][40]
    float*          scf    = (float*)smem;            // [64][68] (epilogue alias)
    float*          bias_s = (float*)(smem + SCF_B);
    int*            hist   = (int*)(smem + SCF_B + 256);

    const int tid  = threadIdx.x;
    const int lane = tid & 63;
    const int rw   = tid >> 6;
    const int blk  = blockIdx.x;
    const int b    = blk & 15;
    const int r    = blk >> 4;                 // output row 0..63

    if (tid < 64) { bias_s[tid] = bias[tid]; hist[tid] = 0; }

    // ---- staging assignment: 192 threads cover [3 slab rows][64 w] ----
    const int  r0   = tid >> 6;                // 0..3 (3 used)
    const int  w_   = tid & 63;
    const bool smain = (tid < 192);
    const int  gr   = r - 1 + r0;              // input row -1..64
    const bool rok  = smain && (gr >= 0) && (gr < 64);
    const float* xbase = x + (((size_t)(b * 256) * 64 + gr) * 64 + w_);
    unsigned short* sdst = xs + (r0 * 66 + (w_ + 1)) * CSTR;

    auto stage = [&](int q) {
        if (smain) {
            const float* p = xbase + (size_t)q * 32 * 4096;
            if (rok) {
#pragma unroll
                for (int bt = 0; bt < 4; ++bt) {
                    float v0 = p[(bt*8+0)*4096], v1 = p[(bt*8+1)*4096];
                    float v2 = p[(bt*8+2)*4096], v3 = p[(bt*8+3)*4096];
                    float v4 = p[(bt*8+4)*4096], v5 = p[(bt*8+5)*4096];
                    float v6 = p[(bt*8+6)*4096], v7 = p[(bt*8+7)*4096];
                    uint4 pk;
                    pk.x = (unsigned)f2h_bits(v0) | ((unsigned)f2h_bits(v1) << 16);
                    pk.y = (unsigned)f2h_bits(v2) | ((unsigned)f2h_bits(v3) << 16);
                    pk.z = (unsigned)f2h_bits(v4) | ((unsigned)f2h_bits(v5) << 16);
                    pk.w = (unsigned)f2h_bits(v6) | ((unsigned)f2h_bits(v7) << 16);
                    *(uint4*)(sdst + bt * 8) = pk;
                }
            } else {
                uint4 z = {0, 0, 0, 0};
#pragma unroll
                for (int bt = 0; bt < 4; ++bt) *(uint4*)(sdst + bt * 8) = z;
            }
        } else if (tid < 192 + 24) {           // halo cols w'=0,65: 3x2x4 uint4
            int idx = tid - 192;
            int hr = idx >> 3, hc = (idx >> 2) & 1, hg = idx & 3;
            uint4 z = {0, 0, 0, 0};
            *(uint4*)(xs + (hr * 66 + hc * 65) * CSTR + hg * 8) = z;
        }
    };

    const int ph = rw >> 1;                    // position half (32 pos)
    const int eh = rw & 1;                     // expert half (32 experts)

    f32x4 acc[2][2];
#pragma unroll
    for (int mt = 0; mt < 2; ++mt)
#pragma unroll
        for (int nt = 0; nt < 2; ++nt) acc[mt][nt] = (f32x4){0.f, 0.f, 0.f, 0.f};

    // ---- K loop: 8 chunks of 32 channels, 9 taps each ----
#pragma unroll 1
    for (int q = 0; q < 8; ++q) {
        // B fragments for this chunk -> registers (L2-hot, 294KB total)
        uint4 Bf[18];
#pragma unroll
        for (int t = 0; t < 9; ++t)
#pragma unroll
            for (int ntl = 0; ntl < 2; ++ntl)
                Bf[t * 2 + ntl] = ((const uint4*)wB)
                    [((q * 9 + t) * 4 + eh * 2 + ntl) * 64 + lane];

        __syncthreads();                       // xs free (prev compute done)
        stage(q);
        __syncthreads();                       // slab ready

#pragma unroll
        for (int t = 0; t < 9; ++t) {
            const int kh = t / 3, kw = t % 3;
            const unsigned short* abase =
                xs + (kh * 66 + kw + ph * 32 + (lane & 15)) * CSTR + (lane >> 4) * 8;
            half8 afr[2];
#pragma unroll
            for (int mt = 0; mt < 2; ++mt)
                afr[mt] = *(const half8*)(abase + mt * 16 * CSTR);
#pragma unroll
            for (int ntl = 0; ntl < 2; ++ntl) {
                half8 bfr;
                __builtin_memcpy(&bfr, &Bf[t * 2 + ntl], 16);
#pragma unroll
                for (int mt = 0; mt < 2; ++mt)
                    acc[mt][ntl] = __builtin_amdgcn_mfma_f32_16x16x32_f16(
                        afr[mt], bfr, acc[mt][ntl], 0, 0, 0);
            }
        }
    }

    // ---- epilogue: sigmoid -> fp32 scores in LDS (aliases xs) ----
    __syncthreads();                           // all waves done reading xs
#pragma unroll
    for (int mt = 0; mt < 2; ++mt)
#pragma unroll
        for (int nt = 0; nt < 2; ++nt)
#pragma unroll
            for (int rr = 0; rr < 4; ++rr) {
                float v = acc[mt][nt][rr];
                float s = 1.f / (1.f + __builtin_amdgcn_exp2f(-v * LOG2E));
                int p = ph * 32 + mt * 16 + ((lane >> 4) << 2) + rr;
                int e = eh * 32 + nt * 16 + (lane & 15);
                scf[p * SSTR + e] = s;
            }
    __syncthreads();

    if (tid < 64) {
        // top-8 of 64; jax tie-break (lower idx first): ascending scan + strict >
        const float* row = scf + tid * SSTR;
        float tv[8];
        int   ti[8];
#pragma unroll
        for (int k = 0; k < 8; ++k) { tv[k] = -3.0e38f; ti[k] = 0; }
#pragma unroll
        for (int j4 = 0; j4 < 16; ++j4) {
            f32x4 blkv = *(const f32x4*)(row + j4 * 4);
#pragma unroll
            for (int j = 0; j < 4; ++j) {
                int   e  = j4 * 4 + j;
                float bs = blkv[j] + bias_s[e];
                if (bs > tv[7]) {
                    tv[7] = bs; ti[7] = e;
#pragma unroll
                    for (int k = 7; k > 0; --k) {
                        float fa = tv[k - 1], fb = tv[k];
                        int   ia = ti[k - 1], ib = ti[k];
                        bool  sw = fb > fa;
                        tv[k - 1] = sw ? fb : fa; tv[k] = sw ? fa : fb;
                        ti[k - 1] = sw ? ib : ia; ti[k] = sw ? ia : ib;
                    }
                }
            }
        }
        // softmax over UNbiased scores of the selected 8
        float u[8], mx = -3.0e38f;
#pragma unroll
        for (int k = 0; k < 8; ++k) { u[k] = tv[k] - bias_s[ti[k]]; mx = fmaxf(mx, u[k]); }
        float ex[8], sum = 0.f;
#pragma unroll
        for (int k = 0; k < 8; ++k) { ex[k] = __builtin_amdgcn_exp2f((u[k] - mx) * LOG2E); sum += ex[k]; }
        float inv = 1.f / sum;

        int obase = b * 32768 + r * 64 + tid;  // [b][k][h=r][w=tid]
#pragma unroll
        for (int k = 0; k < 8; ++k) {
            out[obase + k * 4096]          = ex[k] * inv;     // weights
            out[524288 + obase + k * 4096] = (float)ti[k];    // indices (as f32)
            atomicAdd(&hist[ti[k]], 1);
        }
    }
    __syncthreads();
    if (tid < 64) atomicAdd(out + 1048576 + tid, (float)hist[tid]);  // counts
}

// ---------------------------------------------------------------------------
extern "C" void kernel_launch(void* const* d_in, const int* in_sizes, int n_in,
                              void* d_out, int out_size, void* d_ws, size_t ws_size,
                              hipStream_t stream) {
    const float* x    = (const float*)d_in[0];
    const float* gw   = (const float*)d_in[1];
    const float* bias = (const float*)d_in[2];
    float* out = (float*)d_out;
    unsigned short* wB = (unsigned short*)d_ws;   // 294912 B

    hipMemsetAsync((char*)d_out + (size_t)1048576 * sizeof(float), 0,
                   64 * sizeof(float), stream);   // counts accumulate from 0
    gate_prep<<<72, 256, 0, stream>>>(gw, wB);
    gate_main<<<1024, 256, 0, stream>>>(x, bias, wB, out);
}